// Round 1
// baseline (4250.478 us; speedup 1.0000x reference)
//
#include <hip/hip_runtime.h>
#include <stdint.h>

typedef unsigned short u16;
typedef short v8s __attribute__((ext_vector_type(8)));
typedef float v4f __attribute__((ext_vector_type(4)));

#define DI static __device__ __forceinline__

DI u16 f2bf(float x){ union{float f; uint32_t u;} c; c.f = x; uint32_t r = c.u + 0x7fffu + ((c.u >> 16) & 1u); return (u16)(r >> 16); }
DI float bf2f(u16 b){ union{float f; uint32_t u;} c; c.u = ((uint32_t)b) << 16; return c.f; }
DI float gelu_f(float x){ return 0.5f * x * (1.0f + erff(x * 0.70710678118654752f)); }
DI float sigm(float x){ return 1.0f / (1.0f + expf(-x)); }

// ---------------------------------------------------------------------------
// Transpose + bf16 hi/lo split: W (K x N, f32) -> hi,lo (N x K, bf16 bits)
// ---------------------------------------------------------------------------
__global__ __launch_bounds__(256) void transpose_split_kernel(
    const float* __restrict__ W, u16* __restrict__ hi, u16* __restrict__ lo, int K, int N)
{
    __shared__ float t[32][33];
    int n0 = blockIdx.x * 32, k0 = blockIdx.y * 32;
    int tx = threadIdx.x & 31, ty = threadIdx.x >> 5; // 32 x 8
    #pragma unroll
    for (int i = 0; i < 4; i++) {
        int k = k0 + ty + i * 8, n = n0 + tx;
        float v = (k < K && n < N) ? W[(size_t)k * N + n] : 0.f;
        t[ty + i * 8][tx] = v;
    }
    __syncthreads();
    #pragma unroll
    for (int i = 0; i < 4; i++) {
        int n = n0 + ty + i * 8, k = k0 + tx;
        if (n < N && k < K) {
            float v = t[tx][ty + i * 8];
            u16 h = f2bf(v);
            hi[(size_t)n * K + k] = h;
            lo[(size_t)n * K + k] = f2bf(v - bf2f(h));
        }
    }
}

// ---------------------------------------------------------------------------
// Embedding gathers + zero-init of encoder h ping-pong buffer 0
// blocks: [0,2048) enc rows (b*64+s), [2048,4064) dec rows (t*32+b), [4064,4192) zero h
// ---------------------------------------------------------------------------
__global__ __launch_bounds__(256) void gather_init_kernel(
    const int* __restrict__ src, const int* __restrict__ trg,
    const float* __restrict__ enc_embed, const float* __restrict__ dec_embed,
    float* __restrict__ embE, float* __restrict__ embD,
    float* __restrict__ hF0, float* __restrict__ hB0)
{
    int r = blockIdx.x, tx = threadIdx.x;
    if (r < 2048) {
        int idx = src[r];
        embE[(size_t)r * 256 + tx] = enc_embed[(size_t)idx * 256 + tx];
    } else if (r < 4064) {
        int rd = r - 2048;
        int t = rd >> 5, b = rd & 31;
        int tok = trg[b * 64 + t];
        embD[(size_t)rd * 256 + tx] = dec_embed[(size_t)tok * 256 + tx];
    } else {
        int i = (r - 4064) * 256 + tx; // [0, 32768)
        if (i < 16384) hF0[i] = 0.f; else hB0[i - 16384] = 0.f;
    }
}

// ---------------------------------------------------------------------------
// GEMM: C = act(A @ B + bias).  A: f32 MxK row-major.  B passed pre-transposed
// and bf16-split: Bhi/Blo are (N x K) bf16.  3-MFMA compensated product:
// AhiBhi + AhiBlo + AloBhi  (error ~1e-5 rel, vs ~4e-3 for plain bf16).
// Tiles: 128x128, BK=32, 256 threads = 4 waves (2x2 of 64x64 per wave).
// remap: C row r=t*32+b is scattered to output row b*64+t+1 (decoder layout).
// ---------------------------------------------------------------------------
__global__ __launch_bounds__(256) void gemm_bf16x3_kernel(
    const float* __restrict__ A, const u16* __restrict__ Bhi, const u16* __restrict__ Blo,
    const float* __restrict__ bias, float* __restrict__ C,
    int M, int N, int K, int act_gelu, int remap)
{
    __shared__ u16 Ah[128 * 40], Al[128 * 40], Bh[128 * 40], Bl[128 * 40];
    const int tid = threadIdx.x;
    const int lane = tid & 63, wave = tid >> 6;
    const int lm = lane & 15, quad = lane >> 4;
    const int wm = wave >> 1, wn = wave & 1;
    const int m0 = blockIdx.y * 128, n0 = blockIdx.x * 128;
    const int sr = tid >> 1;          // staging row 0..127
    const int sh = (tid & 1) * 16;    // staging k-offset 0/16

    v4f acc[4][4];
    #pragma unroll
    for (int i = 0; i < 4; i++)
        #pragma unroll
        for (int j = 0; j < 4; j++)
            #pragma unroll
            for (int r = 0; r < 4; r++) acc[i][j][r] = 0.f;

    for (int k0 = 0; k0 < K; k0 += 32) {
        // ---- stage A (f32 -> bf16 hi/lo) ----
        {
            float v[16];
            const int gm = m0 + sr;
            if (gm < M) {
                const float4* p = (const float4*)(A + (size_t)gm * K + k0 + sh);
                #pragma unroll
                for (int i = 0; i < 4; i++) {
                    float4 q = p[i];
                    v[4*i] = q.x; v[4*i+1] = q.y; v[4*i+2] = q.z; v[4*i+3] = q.w;
                }
            } else {
                #pragma unroll
                for (int i = 0; i < 16; i++) v[i] = 0.f;
            }
            v8s h0, h1, l0, l1;
            #pragma unroll
            for (int i = 0; i < 8; i++) {
                u16 ha = f2bf(v[i]);     u16 la = f2bf(v[i] - bf2f(ha));
                u16 hb = f2bf(v[8+i]);   u16 lb = f2bf(v[8+i] - bf2f(hb));
                h0[i] = (short)ha; l0[i] = (short)la; h1[i] = (short)hb; l1[i] = (short)lb;
            }
            *(v8s*)&Ah[sr * 40 + sh] = h0; *(v8s*)&Ah[sr * 40 + sh + 8] = h1;
            *(v8s*)&Al[sr * 40 + sh] = l0; *(v8s*)&Al[sr * 40 + sh + 8] = l1;
        }
        // ---- stage B (already bf16 hi/lo, N x K) ----
        {
            const int gn = n0 + sr;
            v8s b0, b1, c0, c1;
            if (gn < N) {
                const v8s* ph = (const v8s*)(Bhi + (size_t)gn * K + k0 + sh);
                const v8s* pl = (const v8s*)(Blo + (size_t)gn * K + k0 + sh);
                b0 = ph[0]; b1 = ph[1]; c0 = pl[0]; c1 = pl[1];
            } else {
                #pragma unroll
                for (int i = 0; i < 8; i++) { b0[i] = 0; b1[i] = 0; c0[i] = 0; c1[i] = 0; }
            }
            *(v8s*)&Bh[sr * 40 + sh] = b0; *(v8s*)&Bh[sr * 40 + sh + 8] = b1;
            *(v8s*)&Bl[sr * 40 + sh] = c0; *(v8s*)&Bl[sr * 40 + sh + 8] = c1;
        }
        __syncthreads();
        // ---- fragments + MFMA ----
        v8s ah[4], al[4], bh[4], bl[4];
        #pragma unroll
        for (int mt = 0; mt < 4; mt++) {
            int off = (wm * 64 + mt * 16 + lm) * 40 + quad * 8;
            ah[mt] = *(v8s*)&Ah[off]; al[mt] = *(v8s*)&Al[off];
        }
        #pragma unroll
        for (int nt = 0; nt < 4; nt++) {
            int off = (wn * 64 + nt * 16 + lm) * 40 + quad * 8;
            bh[nt] = *(v8s*)&Bh[off]; bl[nt] = *(v8s*)&Bl[off];
        }
        #pragma unroll
        for (int mt = 0; mt < 4; mt++)
            #pragma unroll
            for (int nt = 0; nt < 4; nt++) {
                v4f a = acc[mt][nt];
                a = __builtin_amdgcn_mfma_f32_16x16x32_bf16(ah[mt], bh[nt], a, 0, 0, 0);
                a = __builtin_amdgcn_mfma_f32_16x16x32_bf16(ah[mt], bl[nt], a, 0, 0, 0);
                a = __builtin_amdgcn_mfma_f32_16x16x32_bf16(al[mt], bh[nt], a, 0, 0, 0);
                acc[mt][nt] = a;
            }
        __syncthreads();
    }
    // ---- epilogue ----
    #pragma unroll
    for (int nt = 0; nt < 4; nt++) {
        int col = n0 + wn * 64 + nt * 16 + lm;
        if (col >= N) continue;
        float bv = bias ? bias[col] : 0.f;
        #pragma unroll
        for (int mt = 0; mt < 4; mt++) {
            int rbase = m0 + wm * 64 + mt * 16 + quad * 4;
            #pragma unroll
            for (int r = 0; r < 4; r++) {
                int row = rbase + r;
                if (row < M) {
                    float v = acc[mt][nt][r] + bv;
                    if (act_gelu) v = gelu_f(v);
                    size_t drow = remap ? (size_t)((row & 31) * 64 + (row >> 5) + 1) : (size_t)row;
                    C[drow * (size_t)N + col] = v;
                }
            }
        }
    }
}

// ---------------------------------------------------------------------------
// GRU gate math shared by encoder/decoder cells
// ---------------------------------------------------------------------------
DI float gru_out(float i0, float i1, float i2, float g0, float g1, float g2,
                 float b0, float b1, float b2, float hprev)
{
    float r = sigm(i0 + g0 + b0);
    float z = sigm(i1 + g1 + b1);
    float n = tanhf(i2 + r * (g2 + b2));
    return (1.f - z) * n + z * hprev;
}

// One encoder timestep, both directions. 128 blocks (64 fwd + 64 bwd), 8 H-cols
// per block, thread (b, jj). h staged through LDS in 128-k tiles (pad 132).
__global__ __launch_bounds__(256) void enc_step_kernel(
    int step,
    const float* __restrict__ hFin, float* __restrict__ hFout,
    const float* __restrict__ hBin, float* __restrict__ hBout,
    const float* __restrict__ giF, const float* __restrict__ giB,
    const float* __restrict__ Wh_f, const float* __restrict__ Wh_b,
    const float* __restrict__ bh_f, const float* __restrict__ bh_b,
    const int* __restrict__ src_lens,
    float* __restrict__ wrep, float* __restrict__ sent)
{
    const int dir = blockIdx.x >> 6;
    const int jb = (blockIdx.x & 63) * 8;
    const int tid = threadIdx.x;
    const int b = tid >> 3, jj = tid & 7, j = jb + jj;
    const float* hin = dir ? hBin : hFin;
    const float* gi  = dir ? giB : giF;
    const float* Wh  = dir ? Wh_b : Wh_f;
    const float* bh  = dir ? bh_b : bh_f;
    float* hout = dir ? hBout : hFout;
    const int t_eff = dir ? (63 - step) : step;

    __shared__ float hl[32 * 132];
    float g0 = 0.f, g1 = 0.f, g2 = 0.f;
    for (int kt = 0; kt < 512; kt += 128) {
        __syncthreads();
        #pragma unroll
        for (int w = 0; w < 4; w++) {
            int flat = (tid + w * 256) * 4;
            int bb = flat >> 7, kk = flat & 127;
            float4 fv = *(const float4*)(hin + bb * 512 + kt + kk);
            *(float4*)&hl[bb * 132 + kk] = fv;
        }
        __syncthreads();
        const float* w0base = Wh + (size_t)kt * 1536 + j;
        #pragma unroll 2
        for (int kk = 0; kk < 128; kk += 4) {
            float4 hv = *(const float4*)&hl[b * 132 + kk];
            const float* w = w0base + (size_t)kk * 1536;
            g0 += hv.x * w[0];    g1 += hv.x * w[512];  g2 += hv.x * w[1024];
            g0 += hv.y * w[1536]; g1 += hv.y * w[2048]; g2 += hv.y * w[2560];
            g0 += hv.z * w[3072]; g1 += hv.z * w[3584]; g2 += hv.z * w[4096];
            g0 += hv.w * w[4608]; g1 += hv.w * w[5120]; g2 += hv.w * w[5632];
        }
    }
    size_t gbase = ((size_t)b * 64 + t_eff) * 1536 + j;
    float hprev = hin[b * 512 + j];
    float hnew = gru_out(gi[gbase], gi[gbase + 512], gi[gbase + 1024],
                         g0, g1, g2, bh[j], bh[512 + j], bh[1024 + j], hprev);
    int len = src_lens[b]; if (len < 1) len = 1;
    bool valid = t_eff < len;
    float hkeep = valid ? hnew : hprev;
    hout[b * 512 + j] = hkeep;
    wrep[((size_t)b * 64 + t_eff) * 1024 + dir * 512 + j] = valid ? hnew : 0.f;
    if (step == 63) sent[b * 1024 + dir * 512 + j] = hkeep;
}

// Decoder GRU cell (pre-attention): h_t = GRU(e_t, hid_{t-1}). 64 blocks.
__global__ __launch_bounds__(256) void dec_cell_kernel(
    int t, const float* __restrict__ HID, const float* __restrict__ giD,
    const float* __restrict__ Wh, const float* __restrict__ bh,
    float* __restrict__ htmp)
{
    const int jb = blockIdx.x * 8;
    const int tid = threadIdx.x;
    const int b = tid >> 3, jj = tid & 7, j = jb + jj;
    const float* hin = HID + (size_t)t * 16384;

    __shared__ float hl[32 * 132];
    float g0 = 0.f, g1 = 0.f, g2 = 0.f;
    for (int kt = 0; kt < 512; kt += 128) {
        __syncthreads();
        #pragma unroll
        for (int w = 0; w < 4; w++) {
            int flat = (tid + w * 256) * 4;
            int bb = flat >> 7, kk = flat & 127;
            float4 fv = *(const float4*)(hin + bb * 512 + kt + kk);
            *(float4*)&hl[bb * 132 + kk] = fv;
        }
        __syncthreads();
        const float* w0base = Wh + (size_t)kt * 1536 + j;
        #pragma unroll 2
        for (int kk = 0; kk < 128; kk += 4) {
            float4 hv = *(const float4*)&hl[b * 132 + kk];
            const float* w = w0base + (size_t)kk * 1536;
            g0 += hv.x * w[0];    g1 += hv.x * w[512];  g2 += hv.x * w[1024];
            g0 += hv.y * w[1536]; g1 += hv.y * w[2048]; g2 += hv.y * w[2560];
            g0 += hv.z * w[3072]; g1 += hv.z * w[3584]; g2 += hv.z * w[4096];
            g0 += hv.w * w[4608]; g1 += hv.w * w[5120]; g2 += hv.w * w[5632];
        }
    }
    size_t gbase = ((size_t)t * 32 + b) * 1536 + j;
    float hprev = hin[b * 512 + j];
    float hnew = gru_out(giD[gbase], giD[gbase + 512], giD[gbase + 1024],
                         g0, g1, g2, bh[j], bh[512 + j], bh[1024 + j], hprev);
    htmp[b * 512 + j] = hnew;
}

// Decoder attention + hid write: 32 blocks (one per batch row).
__global__ __launch_bounds__(256) void dec_attn_kernel(
    int t, const float* __restrict__ htmp, const float* __restrict__ Kmat,
    const float* __restrict__ Vmat, const float* __restrict__ Wq,
    const float* __restrict__ bq, float* __restrict__ HID)
{
    const int b = blockIdx.x, tid = threadIdx.x;
    __shared__ float hl[512];
    __shared__ float Kt[64 * 68];
    __shared__ float qp[256];
    __shared__ float qv[64];
    __shared__ float aw[64];

    hl[tid] = htmp[b * 512 + tid];
    hl[256 + tid] = htmp[b * 512 + 256 + tid];
    #pragma unroll
    for (int w = 0; w < 4; w++) {
        int flat = (tid + w * 256) * 4;
        int s = flat >> 6, d = flat & 63;
        float4 fv = *(const float4*)(Kmat + ((size_t)b * 64 + s) * 64 + d);
        *(float4*)&Kt[s * 68 + d] = fv;
    }
    __syncthreads();
    // q = h @ Wq (+bq), K-split by 4
    {
        int o = tid >> 2, part = tid & 3;
        float acc = 0.f;
        const float* wq = Wq + (size_t)(part * 128) * 64 + o;
        int base = part * 128;
        for (int k = 0; k < 128; k++) acc += hl[base + k] * wq[(size_t)k * 64];
        qp[tid] = acc;
    }
    __syncthreads();
    if (tid < 64) qv[tid] = qp[tid * 4] + qp[tid * 4 + 1] + qp[tid * 4 + 2] + qp[tid * 4 + 3] + bq[tid];
    __syncthreads();
    if (tid < 64) {
        float sc = 0.f;
        #pragma unroll 8
        for (int d = 0; d < 64; d++) sc += qv[d] * Kt[tid * 68 + d];
        sc *= 0.125f; // 1/sqrt(64)
        float mx = sc;
        #pragma unroll
        for (int m = 32; m >= 1; m >>= 1) mx = fmaxf(mx, __shfl_xor(mx, m));
        float e = expf(sc - mx);
        float sm = e;
        #pragma unroll
        for (int m = 32; m >= 1; m >>= 1) sm += __shfl_xor(sm, m);
        aw[tid] = e / sm;
    }
    __syncthreads();
    float* hid = HID + ((size_t)(t + 1)) * 16384 + (size_t)b * 512;
    #pragma unroll
    for (int c = 0; c < 2; c++) {
        int jcol = tid + c * 256;
        float acc = 0.f;
        for (int s = 0; s < 64; s++) acc += aw[s] * Vmat[((size_t)b * 64 + s) * 512 + jcol];
        hid[jcol] = hl[jcol] + acc;
    }
}

// out[:, 0, :] = 0
__global__ __launch_bounds__(256) void zero_col0_kernel(float* __restrict__ out)
{
    int gid = blockIdx.x * 256 + threadIdx.x;
    if (gid < 32 * 32000) {
        int b = gid / 32000, col = gid % 32000;
        out[(size_t)b * 64 * 32000 + col] = 0.f;
    }
}

// ---------------------------------------------------------------------------
extern "C" void kernel_launch(void* const* d_in, const int* in_sizes, int n_in,
                              void* d_out, int out_size, void* d_ws, size_t ws_size,
                              hipStream_t stream)
{
    const int*   src       = (const int*)d_in[0];
    const int*   trg       = (const int*)d_in[1];
    const int*   src_lens  = (const int*)d_in[2];
    const float* enc_embed = (const float*)d_in[3];
    const float* Wi_f  = (const float*)d_in[4];
    const float* Wh_f  = (const float*)d_in[5];
    const float* bi_f  = (const float*)d_in[6];
    const float* bh_f  = (const float*)d_in[7];
    const float* Wi_b  = (const float*)d_in[8];
    const float* Wh_b  = (const float*)d_in[9];
    const float* bi_b  = (const float*)d_in[10];
    const float* bh_b  = (const float*)d_in[11];
    const float* W_e2d = (const float*)d_in[12];
    const float* b_e2d = (const float*)d_in[13];
    const float* dec_embed = (const float*)d_in[14];
    const float* Wi_d  = (const float*)d_in[15];
    const float* Wh_d  = (const float*)d_in[16];
    const float* bi_d  = (const float*)d_in[17];
    const float* bh_d  = (const float*)d_in[18];
    const float* Wq    = (const float*)d_in[19];
    const float* bq    = (const float*)d_in[20];
    const float* Wk    = (const float*)d_in[21];
    const float* bk    = (const float*)d_in[22];
    const float* Wv    = (const float*)d_in[23];
    const float* bv    = (const float*)d_in[24];
    const float* W1    = (const float*)d_in[25];
    const float* b1    = (const float*)d_in[26];
    const float* W2    = (const float*)d_in[27];
    const float* b2    = (const float*)d_in[28];
    float* out = (float*)d_out;

    // workspace layout (~133 MB)
    float* f = (float*)d_ws;
    float* embE = f; f += 524288;     // 2048 x 256
    float* embD = f; f += 516096;     // 2016 x 256
    float* giF  = f; f += 3145728;    // 2048 x 1536
    float* giB  = f; f += 3145728;
    float* giD  = f; f += 3096576;    // 2016 x 1536
    float* wrep = f; f += 2097152;    // 2048 x 1024
    float* sent = f; f += 32768;      // 32 x 1024
    float* hF   = f; f += 32768;      // 2 x 32 x 512 ping-pong
    float* hB   = f; f += 32768;
    float* Kmat = f; f += 131072;     // 2048 x 64
    float* Vmat = f; f += 1048576;    // 2048 x 512
    float* HID  = f; f += 1048576;    // 64 x 32 x 512 (slot 0 = hidden0)
    float* htmp = f; f += 16384;      // 32 x 512
    float* G1   = f; f += 1032192;    // 2016 x 512
    u16* u = (u16*)f;
    u16* WiF_hi = u; u += 393216;  u16* WiF_lo = u; u += 393216;  // 1536 x 256
    u16* WiB_hi = u; u += 393216;  u16* WiB_lo = u; u += 393216;
    u16* WiD_hi = u; u += 393216;  u16* WiD_lo = u; u += 393216;
    u16* Wk_hi  = u; u += 65536;   u16* Wk_lo  = u; u += 65536;   // 64 x 1024
    u16* Wv_hi  = u; u += 524288;  u16* Wv_lo  = u; u += 524288;  // 512 x 1024
    u16* We_hi  = u; u += 524288;  u16* We_lo  = u; u += 524288;  // 512 x 1024
    u16* W1_hi  = u; u += 262144;  u16* W1_lo  = u; u += 262144;  // 512 x 512
    u16* W2_hi  = u; u += 16384000; u16* W2_lo = u; u += 16384000; // 32000 x 512

    // --- weight transpose + bf16 split ---
    hipLaunchKernelGGL(transpose_split_kernel, dim3(48, 8),   dim3(256), 0, stream, Wi_f,  WiF_hi, WiF_lo, 256, 1536);
    hipLaunchKernelGGL(transpose_split_kernel, dim3(48, 8),   dim3(256), 0, stream, Wi_b,  WiB_hi, WiB_lo, 256, 1536);
    hipLaunchKernelGGL(transpose_split_kernel, dim3(48, 8),   dim3(256), 0, stream, Wi_d,  WiD_hi, WiD_lo, 256, 1536);
    hipLaunchKernelGGL(transpose_split_kernel, dim3(2, 32),   dim3(256), 0, stream, Wk,    Wk_hi,  Wk_lo,  1024, 64);
    hipLaunchKernelGGL(transpose_split_kernel, dim3(16, 32),  dim3(256), 0, stream, Wv,    Wv_hi,  Wv_lo,  1024, 512);
    hipLaunchKernelGGL(transpose_split_kernel, dim3(16, 32),  dim3(256), 0, stream, W_e2d, We_hi,  We_lo,  1024, 512);
    hipLaunchKernelGGL(transpose_split_kernel, dim3(16, 16),  dim3(256), 0, stream, W1,    W1_hi,  W1_lo,  512, 512);
    hipLaunchKernelGGL(transpose_split_kernel, dim3(1000, 16),dim3(256), 0, stream, W2,    W2_hi,  W2_lo,  512, 32000);

    // --- embedding gathers + zero h ---
    hipLaunchKernelGGL(gather_init_kernel, dim3(4192), dim3(256), 0, stream,
                       src, trg, enc_embed, dec_embed, embE, embD, hF, hB);

    // --- input-projection GEMMs (all timesteps batched) ---
    hipLaunchKernelGGL(gemm_bf16x3_kernel, dim3(12, 16), dim3(256), 0, stream,
                       embE, WiF_hi, WiF_lo, bi_f, giF, 2048, 1536, 256, 0, 0);
    hipLaunchKernelGGL(gemm_bf16x3_kernel, dim3(12, 16), dim3(256), 0, stream,
                       embE, WiB_hi, WiB_lo, bi_b, giB, 2048, 1536, 256, 0, 0);
    hipLaunchKernelGGL(gemm_bf16x3_kernel, dim3(12, 16), dim3(256), 0, stream,
                       embD, WiD_hi, WiD_lo, bi_d, giD, 2016, 1536, 256, 0, 0);

    // --- encoder recurrence (64 steps, fwd+bwd fused per launch) ---
    for (int step = 0; step < 64; step++) {
        const float* hFin = hF + (step & 1) * 16384;
        float*       hFout = hF + ((step + 1) & 1) * 16384;
        const float* hBin = hB + (step & 1) * 16384;
        float*       hBout = hB + ((step + 1) & 1) * 16384;
        hipLaunchKernelGGL(enc_step_kernel, dim3(128), dim3(256), 0, stream,
                           step, hFin, hFout, hBin, hBout, giF, giB,
                           Wh_f, Wh_b, bh_f, bh_b, src_lens, wrep, sent);
    }

    // --- K/V projections, decoder init state ---
    hipLaunchKernelGGL(gemm_bf16x3_kernel, dim3(1, 16), dim3(256), 0, stream,
                       wrep, Wk_hi, Wk_lo, bk, Kmat, 2048, 64, 1024, 0, 0);
    hipLaunchKernelGGL(gemm_bf16x3_kernel, dim3(4, 16), dim3(256), 0, stream,
                       wrep, Wv_hi, Wv_lo, bv, Vmat, 2048, 512, 1024, 0, 0);
    hipLaunchKernelGGL(gemm_bf16x3_kernel, dim3(4, 1), dim3(256), 0, stream,
                       sent, We_hi, We_lo, b_e2d, HID, 32, 512, 1024, 1, 0);

    // --- decoder recurrence (63 steps) ---
    for (int t = 0; t < 63; t++) {
        hipLaunchKernelGGL(dec_cell_kernel, dim3(64), dim3(256), 0, stream,
                           t, HID, giD, Wh_d, bh_d, htmp);
        hipLaunchKernelGGL(dec_attn_kernel, dim3(32), dim3(256), 0, stream,
                           t, htmp, Kmat, Vmat, Wq, bq, HID);
    }

    // --- output projection: G1 = gelu(HID[1:] @ W1 + b1); OUT = G1 @ W2 + b2 ---
    hipLaunchKernelGGL(gemm_bf16x3_kernel, dim3(4, 16), dim3(256), 0, stream,
                       HID + 16384, W1_hi, W1_lo, b1, G1, 2016, 512, 512, 1, 0);
    hipLaunchKernelGGL(gemm_bf16x3_kernel, dim3(250, 16), dim3(256), 0, stream,
                       G1, W2_hi, W2_lo, b2, out, 2016, 32000, 512, 0, 1);

    // --- out[:, 0, :] = 0 ---
    hipLaunchKernelGGL(zero_col0_kernel, dim3(4000), dim3(256), 0, stream, out);
}